// Round 1
// baseline (636.809 us; speedup 1.0000x reference)
//
#include <hip/hip_runtime.h>
#include <hip/hip_bf16.h>

#define N_NODES 100000
#define N_EDGES 1600000
#define IN_DIM 128
#define HID 256
#define NUM_GRAPHS 2048
#define M_PAD 100096  // 1564 * 64
#define SCAN_BLOCKS 98  // ceil(100000/1024)

typedef __bf16 bf16x8 __attribute__((ext_vector_type(8)));
typedef float f32x4 __attribute__((ext_vector_type(4)));

__device__ inline unsigned short f2bf(float x) {
    union { __hip_bfloat16 h; unsigned short u; } v;
    v.h = __float2bfloat16(x);
    return v.u;
}
__device__ inline float bf2f(unsigned short u) {
    return __uint_as_float(((unsigned int)u) << 16);
}
__device__ inline int rfl(int x) { return __builtin_amdgcn_readfirstlane(x); }

// ---------------- degree histogram over dst ----------------
__global__ void count_deg_kernel(const int* __restrict__ ei, int* __restrict__ deg) {
    int e = blockIdx.x * blockDim.x + threadIdx.x;
    if (e < N_EDGES) {
        atomicAdd(&deg[ei[N_EDGES + e]], 1);
    }
}

// ---------------- block sums (+ fused dinv) ----------------
__global__ __launch_bounds__(1024) void blocksum_kernel(const int* __restrict__ deg,
                                                        int* __restrict__ bsum,
                                                        float* __restrict__ dinv) {
    int i = blockIdx.x * 1024 + threadIdx.x;
    int v = (i < N_NODES) ? deg[i] : 0;
    if (i < N_NODES) dinv[i] = rsqrtf((float)(v + 1));  // self-loop adds 1
    __shared__ int s[1024];
    int t = threadIdx.x;
    s[t] = v;
    __syncthreads();
#pragma unroll
    for (int off = 512; off > 0; off >>= 1) {
        if (t < off) s[t] += s[t + off];
        __syncthreads();
    }
    if (t == 0) bsum[blockIdx.x] = s[0];
}

__global__ __launch_bounds__(128) void bscan_kernel(int* __restrict__ bsum) {
    __shared__ int s[128];
    int t = threadIdx.x;
    int v = (t < SCAN_BLOCKS) ? bsum[t] : 0;
    s[t] = v;
    __syncthreads();
#pragma unroll
    for (int off = 1; off < 128; off <<= 1) {
        int x = (t >= off) ? s[t - off] : 0;
        __syncthreads();
        s[t] += x;
        __syncthreads();
    }
    if (t < SCAN_BLOCKS) bsum[t] = (t > 0) ? s[t - 1] : 0;  // exclusive
}

__global__ __launch_bounds__(1024) void scanout_kernel(const int* __restrict__ deg,
                                                       const int* __restrict__ bsum,
                                                       int* __restrict__ rowptr) {
    int i = blockIdx.x * 1024 + threadIdx.x;
    int t = threadIdx.x;
    int v = (i < N_NODES) ? deg[i] : 0;
    __shared__ int s[1024];
    s[t] = v;
    __syncthreads();
#pragma unroll
    for (int off = 1; off < 1024; off <<= 1) {
        int x = (t >= off) ? s[t - off] : 0;
        __syncthreads();
        s[t] += x;
        __syncthreads();
    }
    int base = bsum[blockIdx.x];
    int excl = (t > 0) ? s[t - 1] : 0;
    if (i < N_NODES) rowptr[i] = base + excl;
    if (i == N_NODES - 1) rowptr[N_NODES] = base + s[t];
}

// ---------------- bucket fill: CSR src list sorted by dst ----------------
__global__ void fill_kernel(const int* __restrict__ ei, const int* __restrict__ rowptr,
                            int* __restrict__ fill, int* __restrict__ esrc) {
    int e = blockIdx.x * blockDim.x + threadIdx.x;
    if (e < N_EDGES) {
        int dst = ei[N_EDGES + e];
        int pos = rowptr[dst] + atomicAdd(&fill[dst], 1);
        esrc[pos] = ei[e];
    }
}

// ---------------- x -> bf16 ----------------
__global__ void x2bf_kernel(const float* __restrict__ x, unsigned short* __restrict__ xb) {
    size_t i = ((size_t)blockIdx.x * 256 + threadIdx.x) * 4;
    float4 v = *(const float4*)(x + i);
    ushort4 o;
    o.x = f2bf(v.x); o.y = f2bf(v.y); o.z = f2bf(v.z); o.w = f2bf(v.w);
    *(ushort4*)(xb + i) = o;
}

// ---------------- both weight transposes + bf16 splits in one launch ----------
__global__ void wsplit_all_kernel(const float* __restrict__ W1, const float* __restrict__ W2,
                                  unsigned short* __restrict__ W1th, unsigned short* __restrict__ W1tl,
                                  unsigned short* __restrict__ W2th, unsigned short* __restrict__ W2tl) {
    int idx = blockIdx.x * 256 + threadIdx.x;
    if (idx < IN_DIM * 256) {
        int k = idx >> 8, n = idx & 255;
        float w = W1[idx];
        unsigned short h = f2bf(w);
        unsigned short l = f2bf(w - bf2f(h));
        W1th[n * IN_DIM + k] = h;
        W1tl[n * IN_DIM + k] = l;
    } else {
        int i2 = idx - IN_DIM * 256;
        int k = i2 >> 8, n = i2 & 255;
        float w = W2[i2];
        unsigned short h = f2bf(w);
        unsigned short l = f2bf(w - bf2f(h));
        W2th[n * HID + k] = h;
        W2tl[n * HID + k] = l;
    }
}

// ================= fused gather-aggregate + MFMA GEMM + bias + relu ==========
// Block: 256 threads (4 waves). Block owns 64 output rows x ALL 256 cols
// (grid.y==1 so the gather is never duplicated). Each wave aggregates 16
// node rows into an LDS A-tile (bf16 hi [+lo if ASPLIT], XOR-swizzled to kill
// the 16-way stride-K bank conflict), then the MFMA loop reads A from LDS and
// B fragments directly from global (W splits are <=256 KB -> L2-resident).
// ASPLIT: 3-term product (Ah*Bh + Ah*Bl + Al*Bh) else 2-term (Ah*Bh + Ah*Bl).
template <int K, bool ASPLIT>
__global__ __launch_bounds__(256, 3) void fused_layer(const unsigned short* __restrict__ X,
                                                      const int* __restrict__ esrc,
                                                      const int* __restrict__ rowptr,
                                                      const float* __restrict__ dinv,
                                                      const unsigned short* __restrict__ Bh,
                                                      const unsigned short* __restrict__ Bl,
                                                      const float* __restrict__ bias,
                                                      unsigned short* __restrict__ Cout) {
    constexpr int ROWB = K * 2;  // bytes per LDS A row
    __shared__ __align__(16) unsigned char lds[(ASPLIT ? 2 : 1) * 64 * ROWB];
    unsigned char* AhsB = lds;
    unsigned char* AlsB = lds + 64 * ROWB;  // only touched when ASPLIT

    int tid = threadIdx.x;
    int wid = tid >> 6, lane = tid & 63;
    int bm = blockIdx.x * 64;

    // ---------- phase 1: gather + aggregate 16 nodes per wave into LDS ----------
    for (int i = 0; i < 16; i++) {
        int r = wid * 16 + i;                 // local row 0..63
        int node = rfl(bm + r);               // wave-uniform -> scalar addressing
        if constexpr (K == 128) {
            float2 acc = make_float2(0.f, 0.f);
            if (node < N_NODES) {
                float ddst = dinv[node];
                int s = rfl(rowptr[node]);
                int e = rfl(rowptr[node + 1]);
                float w0 = ddst * ddst;
                ushort2 h0 = *((const ushort2*)(X + (size_t)node * 128) + lane);
                acc.x = w0 * bf2f(h0.x);
                acc.y = w0 * bf2f(h0.y);
                int j = s;
                for (; j + 8 <= e; j += 8) {
                    int si[8];
#pragma unroll
                    for (int u = 0; u < 8; u++) si[u] = rfl(esrc[j + u]);
                    ushort2 xv[8];
#pragma unroll
                    for (int u = 0; u < 8; u++)
                        xv[u] = *((const ushort2*)(X + (size_t)si[u] * 128) + lane);
                    float a[8];
#pragma unroll
                    for (int u = 0; u < 8; u++) a[u] = dinv[si[u]] * ddst;
#pragma unroll
                    for (int u = 0; u < 8; u++) {
                        acc.x = fmaf(a[u], bf2f(xv[u].x), acc.x);
                        acc.y = fmaf(a[u], bf2f(xv[u].y), acc.y);
                    }
                }
                for (; j + 4 <= e; j += 4) {
                    int si[4];
#pragma unroll
                    for (int u = 0; u < 4; u++) si[u] = rfl(esrc[j + u]);
                    ushort2 xv[4];
#pragma unroll
                    for (int u = 0; u < 4; u++)
                        xv[u] = *((const ushort2*)(X + (size_t)si[u] * 128) + lane);
                    float a[4];
#pragma unroll
                    for (int u = 0; u < 4; u++) a[u] = dinv[si[u]] * ddst;
#pragma unroll
                    for (int u = 0; u < 4; u++) {
                        acc.x = fmaf(a[u], bf2f(xv[u].x), acc.x);
                        acc.y = fmaf(a[u], bf2f(xv[u].y), acc.y);
                    }
                }
                for (; j < e; j++) {
                    int src = rfl(esrc[j]);
                    float w = dinv[src] * ddst;
                    ushort2 xv = *((const ushort2*)(X + (size_t)src * 128) + lane);
                    acc.x = fmaf(w, bf2f(xv.x), acc.x);
                    acc.y = fmaf(w, bf2f(xv.y), acc.y);
                }
            }
            unsigned bo = ((unsigned)(r * 256 + lane * 4)) ^ (((unsigned)(r & 7)) << 4);
            ushort2 hi, lo;
            hi.x = f2bf(acc.x); lo.x = f2bf(acc.x - bf2f(hi.x));
            hi.y = f2bf(acc.y); lo.y = f2bf(acc.y - bf2f(hi.y));
            *(ushort2*)(AhsB + bo) = hi;
            if (ASPLIT) *(ushort2*)(AlsB + bo) = lo;
        } else {  // K == 256
            float4 acc = make_float4(0.f, 0.f, 0.f, 0.f);
            if (node < N_NODES) {
                float ddst = dinv[node];
                int s = rfl(rowptr[node]);
                int e = rfl(rowptr[node + 1]);
                float w0 = ddst * ddst;
                ushort4 h0 = *((const ushort4*)(X + (size_t)node * 256) + lane);
                acc.x = w0 * bf2f(h0.x);
                acc.y = w0 * bf2f(h0.y);
                acc.z = w0 * bf2f(h0.z);
                acc.w = w0 * bf2f(h0.w);
                int j = s;
                for (; j + 8 <= e; j += 8) {
                    int si[8];
#pragma unroll
                    for (int u = 0; u < 8; u++) si[u] = rfl(esrc[j + u]);
                    ushort4 xv[8];
#pragma unroll
                    for (int u = 0; u < 8; u++)
                        xv[u] = *((const ushort4*)(X + (size_t)si[u] * 256) + lane);
                    float a[8];
#pragma unroll
                    for (int u = 0; u < 8; u++) a[u] = dinv[si[u]] * ddst;
#pragma unroll
                    for (int u = 0; u < 8; u++) {
                        acc.x = fmaf(a[u], bf2f(xv[u].x), acc.x);
                        acc.y = fmaf(a[u], bf2f(xv[u].y), acc.y);
                        acc.z = fmaf(a[u], bf2f(xv[u].z), acc.z);
                        acc.w = fmaf(a[u], bf2f(xv[u].w), acc.w);
                    }
                }
                for (; j + 4 <= e; j += 4) {
                    int si[4];
#pragma unroll
                    for (int u = 0; u < 4; u++) si[u] = rfl(esrc[j + u]);
                    ushort4 xv[4];
#pragma unroll
                    for (int u = 0; u < 4; u++)
                        xv[u] = *((const ushort4*)(X + (size_t)si[u] * 256) + lane);
                    float a[4];
#pragma unroll
                    for (int u = 0; u < 4; u++) a[u] = dinv[si[u]] * ddst;
#pragma unroll
                    for (int u = 0; u < 4; u++) {
                        acc.x = fmaf(a[u], bf2f(xv[u].x), acc.x);
                        acc.y = fmaf(a[u], bf2f(xv[u].y), acc.y);
                        acc.z = fmaf(a[u], bf2f(xv[u].z), acc.z);
                        acc.w = fmaf(a[u], bf2f(xv[u].w), acc.w);
                    }
                }
                for (; j < e; j++) {
                    int src = rfl(esrc[j]);
                    float w = dinv[src] * ddst;
                    ushort4 xv = *((const ushort4*)(X + (size_t)src * 256) + lane);
                    acc.x = fmaf(w, bf2f(xv.x), acc.x);
                    acc.y = fmaf(w, bf2f(xv.y), acc.y);
                    acc.z = fmaf(w, bf2f(xv.z), acc.z);
                    acc.w = fmaf(w, bf2f(xv.w), acc.w);
                }
            }
            unsigned bo = ((unsigned)(r * 512 + lane * 8)) ^ (((unsigned)(r & 7)) << 4);
            ushort4 hi;
            hi.x = f2bf(acc.x); hi.y = f2bf(acc.y);
            hi.z = f2bf(acc.z); hi.w = f2bf(acc.w);
            *(ushort4*)(AhsB + bo) = hi;
        }
    }
    __syncthreads();

    // ---------- phase 2: MFMA GEMM, A from LDS, B fragments from global ----------
    int lrow = lane & 15, quad = lane >> 4;
    f32x4 acc[4][4];
#pragma unroll
    for (int mi = 0; mi < 4; mi++)
#pragma unroll
        for (int ni = 0; ni < 4; ni++) acc[mi][ni] = (f32x4){0.f, 0.f, 0.f, 0.f};

#pragma unroll
    for (int k0 = 0; k0 < K; k0 += 32) {
        bf16x8 ah[4], al[4];
#pragma unroll
        for (int mi = 0; mi < 4; mi++) {
            int r = mi * 16 + lrow;
            unsigned bo = ((unsigned)(r * ROWB + (k0 + quad * 8) * 2)) ^ (((unsigned)(r & 7)) << 4);
            ah[mi] = *(const bf16x8*)(AhsB + bo);
            if (ASPLIT) al[mi] = *(const bf16x8*)(AlsB + bo);
        }
#pragma unroll
        for (int ni = 0; ni < 4; ni++) {
            int rowB = wid * 64 + ni * 16 + lrow;   // output column = B row
            size_t gb = (size_t)rowB * K + k0 + quad * 8;
            bf16x8 bh = *(const bf16x8*)(Bh + gb);
            bf16x8 bl = *(const bf16x8*)(Bl + gb);
#pragma unroll
            for (int mi = 0; mi < 4; mi++) {
                acc[mi][ni] = __builtin_amdgcn_mfma_f32_16x16x32_bf16(ah[mi], bh, acc[mi][ni], 0, 0, 0);
                acc[mi][ni] = __builtin_amdgcn_mfma_f32_16x16x32_bf16(ah[mi], bl, acc[mi][ni], 0, 0, 0);
                if (ASPLIT)
                    acc[mi][ni] = __builtin_amdgcn_mfma_f32_16x16x32_bf16(al[mi], bh, acc[mi][ni], 0, 0, 0);
            }
        }
    }

    // ---------- epilogue: bias + relu + bf16 store ----------
    float bv[4];
#pragma unroll
    for (int ni = 0; ni < 4; ni++) bv[ni] = bias[wid * 64 + ni * 16 + lrow];
#pragma unroll
    for (int mi = 0; mi < 4; mi++) {
        int row0 = bm + mi * 16 + quad * 4;
#pragma unroll
        for (int ni = 0; ni < 4; ni++) {
            int col = wid * 64 + ni * 16 + lrow;
#pragma unroll
            for (int rr = 0; rr < 4; rr++) {
                int row = row0 + rr;
                if (row < N_NODES) {
                    float v = fmaxf(acc[mi][ni][rr] + bv[ni], 0.f);
                    Cout[(size_t)row * 256 + col] = f2bf(v);
                }
            }
        }
    }
}

// ---------------- fused mean-pool (batch sorted, h in bf16) + MLP head ----------
__global__ __launch_bounds__(256) void pool_mlp_kernel(const unsigned short* __restrict__ h,
                                                       const int* __restrict__ batch,
                                                       const float* __restrict__ Wf1,
                                                       const float* __restrict__ bf1,
                                                       const float* __restrict__ Wf2,
                                                       const float* __restrict__ bf2,
                                                       float* __restrict__ out) {
    int g = blockIdx.x;
    int t = threadIdx.x;  // 0..255
    __shared__ int bounds[2];
    if (t < 2) {
        int target = g + t;
        int lo = 0, hi = N_NODES;
        while (lo < hi) {
            int mid = (lo + hi) >> 1;
            if (batch[mid] < target) lo = mid + 1;
            else hi = mid;
        }
        bounds[t] = lo;
    }
    __syncthreads();
    int lo = bounds[0], hi = bounds[1];

    float acc = 0.f;
    for (int n = lo; n < hi; n++) acc += bf2f(h[(size_t)n * HID + t]);
    float inv = (hi > lo) ? 1.0f / (float)(hi - lo) : 0.f;
    __shared__ float p[256];
    p[t] = acc * inv;
    __syncthreads();

    float hv = 0.f;
    if (t < 128) {
        float a = bf1[t];
#pragma unroll 8
        for (int k = 0; k < 256; k++) a = fmaf(p[k], Wf1[k * 128 + t], a);
        hv = fmaxf(a, 0.f) * Wf2[t];
    }
#pragma unroll
    for (int off = 32; off > 0; off >>= 1) hv += __shfl_down(hv, off, 64);
    __shared__ float partial[4];
    if ((t & 63) == 0) partial[t >> 6] = hv;
    __syncthreads();
    if (t == 0) out[g] = partial[0] + partial[1] + bf2[0];
}

extern "C" void kernel_launch(void* const* d_in, const int* in_sizes, int n_in,
                              void* d_out, int out_size, void* d_ws, size_t ws_size,
                              hipStream_t stream) {
    const float* x   = (const float*)d_in[0];
    const int*   ei  = (const int*)d_in[1];
    const int*   bat = (const int*)d_in[2];
    const float* W1  = (const float*)d_in[3];
    const float* b1  = (const float*)d_in[4];
    const float* W2  = (const float*)d_in[5];
    const float* b2  = (const float*)d_in[6];
    const float* Wf1 = (const float*)d_in[7];
    const float* bf1 = (const float*)d_in[8];
    const float* Wf2 = (const float*)d_in[9];
    const float* bf2 = (const float*)d_in[10];
    float* out = (float*)d_out;

    char* ws = (char*)d_ws;
    // layout (peak end ~0x82D5000 = 137 MB; previous version peaked at 162.5 MB):
    //   0x0000000 deg       0x0080000 dinv     0x0100000 rowptr   0x0180000 fill
    //   0x01F0000 bsum
    //   0x0200000 esrc (6.4 MB)
    //   0x0820000 W1th  0x0830000 W1tl  0x0840000 W2th  0x0860000 W2tl
    //   0x0880000 xbf  (25.6 MB)  -- live through fused layer 1 (gather table)
    //   0x2100000 H1bf (51.2 MB)  -- live through fused layer 2 (gather table)
    //   0x5200000 H2bf (51.2 MB)
    int*   deg    = (int*)(ws);
    float* dinv   = (float*)(ws + 0x0080000);
    int*   rowptr = (int*)(ws + 0x0100000);
    int*   fill   = (int*)(ws + 0x0180000);
    int*   bsum   = (int*)(ws + 0x01F0000);
    int*   esrc   = (int*)(ws + 0x0200000);
    unsigned short* W1th = (unsigned short*)(ws + 0x0820000);
    unsigned short* W1tl = (unsigned short*)(ws + 0x0830000);
    unsigned short* W2th = (unsigned short*)(ws + 0x0840000);
    unsigned short* W2tl = (unsigned short*)(ws + 0x0860000);
    unsigned short* xbf  = (unsigned short*)(ws + 0x0880000);
    unsigned short* H1bf = (unsigned short*)(ws + 0x2100000);
    unsigned short* H2bf = (unsigned short*)(ws + 0x5200000);
    (void)ws_size;

    hipMemsetAsync(deg, 0, (size_t)N_NODES * sizeof(int), stream);
    hipMemsetAsync(fill, 0, (size_t)N_NODES * sizeof(int), stream);

    // independent prep
    x2bf_kernel<<<(N_NODES * IN_DIM / 4) / 256, 256, 0, stream>>>(x, xbf);
    wsplit_all_kernel<<<((IN_DIM + HID) * 256) / 256, 256, 0, stream>>>(W1, W2, W1th, W1tl, W2th, W2tl);

    // CSR build
    count_deg_kernel<<<(N_EDGES + 255) / 256, 256, 0, stream>>>(ei, deg);
    blocksum_kernel<<<SCAN_BLOCKS, 1024, 0, stream>>>(deg, bsum, dinv);
    bscan_kernel<<<1, 128, 0, stream>>>(bsum);
    scanout_kernel<<<SCAN_BLOCKS, 1024, 0, stream>>>(deg, bsum, rowptr);
    fill_kernel<<<(N_EDGES + 255) / 256, 256, 0, stream>>>(ei, rowptr, fill, esrc);

    // layer 1 (fused): gather-agg x_bf16 -> LDS, H1bf = bf16(relu((A~X) @ W1 + b1))  [3-term]
    fused_layer<IN_DIM, true><<<M_PAD / 64, 256, 0, stream>>>(xbf, esrc, rowptr, dinv,
                                                              W1th, W1tl, b1, H1bf);

    // layer 2 (fused): gather-agg H1bf -> LDS, H2bf = bf16(relu((A~H1) @ W2 + b2))  [2-term]
    fused_layer<HID, false><<<M_PAD / 64, 256, 0, stream>>>(H1bf, esrc, rowptr, dinv,
                                                            W2th, W2tl, b2, H2bf);

    // pooling + MLP head (bf16 h)
    pool_mlp_kernel<<<NUM_GRAPHS, 256, 0, stream>>>(H2bf, bat, Wf1, bf1, Wf2, bf2, out);
}

// Round 3
// 631.985 us; speedup vs baseline: 1.0076x; 1.0076x over previous
//
#include <hip/hip_runtime.h>
#include <hip/hip_bf16.h>

#define N_NODES 100000
#define N_EDGES 1600000
#define IN_DIM 128
#define HID 256
#define NUM_GRAPHS 2048
#define M_PAD 100096  // 1564 * 64
#define SCAN_BLOCKS 98  // ceil(100000/1024)

typedef __bf16 bf16x8 __attribute__((ext_vector_type(8)));
typedef float f32x4 __attribute__((ext_vector_type(4)));

__device__ inline unsigned short f2bf(float x) {
    union { __hip_bfloat16 h; unsigned short u; } v;
    v.h = __float2bfloat16(x);
    return v.u;
}
__device__ inline float bf2f(unsigned short u) {
    return __uint_as_float(((unsigned int)u) << 16);
}
__device__ inline int rfl(int x) { return __builtin_amdgcn_readfirstlane(x); }

// ---------------- degree histogram over dst ----------------
__global__ void count_deg_kernel(const int* __restrict__ ei, int* __restrict__ deg) {
    int e = blockIdx.x * blockDim.x + threadIdx.x;
    if (e < N_EDGES) {
        atomicAdd(&deg[ei[N_EDGES + e]], 1);
    }
}

// ---------------- block sums (+ fused dinv) ----------------
__global__ __launch_bounds__(1024) void blocksum_kernel(const int* __restrict__ deg,
                                                        int* __restrict__ bsum,
                                                        float* __restrict__ dinv) {
    int i = blockIdx.x * 1024 + threadIdx.x;
    int v = (i < N_NODES) ? deg[i] : 0;
    if (i < N_NODES) dinv[i] = rsqrtf((float)(v + 1));  // self-loop adds 1
    __shared__ int s[1024];
    int t = threadIdx.x;
    s[t] = v;
    __syncthreads();
#pragma unroll
    for (int off = 512; off > 0; off >>= 1) {
        if (t < off) s[t] += s[t + off];
        __syncthreads();
    }
    if (t == 0) bsum[blockIdx.x] = s[0];
}

__global__ __launch_bounds__(128) void bscan_kernel(int* __restrict__ bsum) {
    __shared__ int s[128];
    int t = threadIdx.x;
    int v = (t < SCAN_BLOCKS) ? bsum[t] : 0;
    s[t] = v;
    __syncthreads();
#pragma unroll
    for (int off = 1; off < 128; off <<= 1) {
        int x = (t >= off) ? s[t - off] : 0;
        __syncthreads();
        s[t] += x;
        __syncthreads();
    }
    if (t < SCAN_BLOCKS) bsum[t] = (t > 0) ? s[t - 1] : 0;  // exclusive
}

__global__ __launch_bounds__(1024) void scanout_kernel(const int* __restrict__ deg,
                                                       const int* __restrict__ bsum,
                                                       int* __restrict__ rowptr) {
    int i = blockIdx.x * 1024 + threadIdx.x;
    int t = threadIdx.x;
    int v = (i < N_NODES) ? deg[i] : 0;
    __shared__ int s[1024];
    s[t] = v;
    __syncthreads();
#pragma unroll
    for (int off = 1; off < 1024; off <<= 1) {
        int x = (t >= off) ? s[t - off] : 0;
        __syncthreads();
        s[t] += x;
        __syncthreads();
    }
    int base = bsum[blockIdx.x];
    int excl = (t > 0) ? s[t - 1] : 0;
    if (i < N_NODES) rowptr[i] = base + excl;
    if (i == N_NODES - 1) rowptr[N_NODES] = base + s[t];
}

// ---------------- bucket fill: CSR src list sorted by dst ----------------
__global__ void fill_kernel(const int* __restrict__ ei, const int* __restrict__ rowptr,
                            int* __restrict__ fill, int* __restrict__ esrc) {
    int e = blockIdx.x * blockDim.x + threadIdx.x;
    if (e < N_EDGES) {
        int dst = ei[N_EDGES + e];
        int pos = rowptr[dst] + atomicAdd(&fill[dst], 1);
        esrc[pos] = ei[e];
    }
}

// ---------------- x -> bf16 ----------------
__global__ void x2bf_kernel(const float* __restrict__ x, unsigned short* __restrict__ xb) {
    size_t i = ((size_t)blockIdx.x * 256 + threadIdx.x) * 4;
    float4 v = *(const float4*)(x + i);
    ushort4 o;
    o.x = f2bf(v.x); o.y = f2bf(v.y); o.z = f2bf(v.z); o.w = f2bf(v.w);
    *(ushort4*)(xb + i) = o;
}

// ---------------- both weight transposes + bf16 splits in one launch ----------
__global__ void wsplit_all_kernel(const float* __restrict__ W1, const float* __restrict__ W2,
                                  unsigned short* __restrict__ W1th, unsigned short* __restrict__ W1tl,
                                  unsigned short* __restrict__ W2th, unsigned short* __restrict__ W2tl) {
    int idx = blockIdx.x * 256 + threadIdx.x;
    if (idx < IN_DIM * 256) {
        int k = idx >> 8, n = idx & 255;
        float w = W1[idx];
        unsigned short h = f2bf(w);
        unsigned short l = f2bf(w - bf2f(h));
        W1th[n * IN_DIM + k] = h;
        W1tl[n * IN_DIM + k] = l;
    } else {
        int i2 = idx - IN_DIM * 256;
        int k = i2 >> 8, n = i2 & 255;
        float w = W2[i2];
        unsigned short h = f2bf(w);
        unsigned short l = f2bf(w - bf2f(h));
        W2th[n * HID + k] = h;
        W2tl[n * HID + k] = l;
    }
}

// ---------------- gather agg 128-dim from bf16, writes bf16 hi/lo split ----------
// wave-uniform node/s/e/src via readfirstlane -> scalar addressing for gathers
__global__ __launch_bounds__(256) void agg128_kernel(const unsigned short* __restrict__ X,
                                                     const int* __restrict__ esrc,
                                                     const int* __restrict__ rowptr,
                                                     const float* __restrict__ dinv,
                                                     unsigned short* __restrict__ Ah,
                                                     unsigned short* __restrict__ Al) {
    int node = rfl(blockIdx.x * 4 + (threadIdx.x >> 6));
    int lane = threadIdx.x & 63;
    float ddst = dinv[node];
    int s = rfl(rowptr[node]);
    int e = rfl(rowptr[node + 1]);

    float w0 = ddst * ddst;
    ushort2 h0 = *((const ushort2*)(X + (size_t)node * 128) + lane);
    float2 acc = make_float2(w0 * bf2f(h0.x), w0 * bf2f(h0.y));

    int j = s;
    for (; j + 8 <= e; j += 8) {
        int si[8];
#pragma unroll
        for (int u = 0; u < 8; u++) si[u] = rfl(esrc[j + u]);
        ushort2 xv[8];
#pragma unroll
        for (int u = 0; u < 8; u++)
            xv[u] = *((const ushort2*)(X + (size_t)si[u] * 128) + lane);
        float a[8];
#pragma unroll
        for (int u = 0; u < 8; u++) a[u] = dinv[si[u]] * ddst;
#pragma unroll
        for (int u = 0; u < 8; u++) {
            acc.x = fmaf(a[u], bf2f(xv[u].x), acc.x);
            acc.y = fmaf(a[u], bf2f(xv[u].y), acc.y);
        }
    }
    for (; j + 4 <= e; j += 4) {
        int si[4];
#pragma unroll
        for (int u = 0; u < 4; u++) si[u] = rfl(esrc[j + u]);
        ushort2 xv[4];
#pragma unroll
        for (int u = 0; u < 4; u++)
            xv[u] = *((const ushort2*)(X + (size_t)si[u] * 128) + lane);
        float a[4];
#pragma unroll
        for (int u = 0; u < 4; u++) a[u] = dinv[si[u]] * ddst;
#pragma unroll
        for (int u = 0; u < 4; u++) {
            acc.x = fmaf(a[u], bf2f(xv[u].x), acc.x);
            acc.y = fmaf(a[u], bf2f(xv[u].y), acc.y);
        }
    }
    for (; j < e; j++) {
        int src = rfl(esrc[j]);
        float w = dinv[src] * ddst;
        ushort2 xv = *((const ushort2*)(X + (size_t)src * 128) + lane);
        acc.x = fmaf(w, bf2f(xv.x), acc.x);
        acc.y = fmaf(w, bf2f(xv.y), acc.y);
    }
    size_t o = (size_t)node * 128 + lane * 2;
    ushort2 hi, lo;
    hi.x = f2bf(acc.x); lo.x = f2bf(acc.x - bf2f(hi.x));
    hi.y = f2bf(acc.y); lo.y = f2bf(acc.y - bf2f(hi.y));
    *(ushort2*)(Ah + o) = hi;
    *(ushort2*)(Al + o) = lo;
}

// ---------------- gather agg 256-dim from bf16, writes bf16 (hi only) ----------
__global__ __launch_bounds__(256) void agg256_kernel(const unsigned short* __restrict__ H,
                                                     const int* __restrict__ esrc,
                                                     const int* __restrict__ rowptr,
                                                     const float* __restrict__ dinv,
                                                     unsigned short* __restrict__ Ah) {
    int node = rfl(blockIdx.x * 4 + (threadIdx.x >> 6));
    int lane = threadIdx.x & 63;
    float ddst = dinv[node];
    int s = rfl(rowptr[node]);
    int e = rfl(rowptr[node + 1]);

    float w0 = ddst * ddst;
    ushort4 h0 = *((const ushort4*)(H + (size_t)node * 256) + lane);
    float4 acc = make_float4(w0 * bf2f(h0.x), w0 * bf2f(h0.y),
                             w0 * bf2f(h0.z), w0 * bf2f(h0.w));

    int j = s;
    for (; j + 8 <= e; j += 8) {
        int si[8];
#pragma unroll
        for (int u = 0; u < 8; u++) si[u] = rfl(esrc[j + u]);
        ushort4 xv[8];
#pragma unroll
        for (int u = 0; u < 8; u++)
            xv[u] = *((const ushort4*)(H + (size_t)si[u] * 256) + lane);
        float a[8];
#pragma unroll
        for (int u = 0; u < 8; u++) a[u] = dinv[si[u]] * ddst;
#pragma unroll
        for (int u = 0; u < 8; u++) {
            acc.x = fmaf(a[u], bf2f(xv[u].x), acc.x);
            acc.y = fmaf(a[u], bf2f(xv[u].y), acc.y);
            acc.z = fmaf(a[u], bf2f(xv[u].z), acc.z);
            acc.w = fmaf(a[u], bf2f(xv[u].w), acc.w);
        }
    }
    for (; j + 4 <= e; j += 4) {
        int si[4];
#pragma unroll
        for (int u = 0; u < 4; u++) si[u] = rfl(esrc[j + u]);
        ushort4 xv[4];
#pragma unroll
        for (int u = 0; u < 4; u++)
            xv[u] = *((const ushort4*)(H + (size_t)si[u] * 256) + lane);
        float a[4];
#pragma unroll
        for (int u = 0; u < 4; u++) a[u] = dinv[si[u]] * ddst;
#pragma unroll
        for (int u = 0; u < 4; u++) {
            acc.x = fmaf(a[u], bf2f(xv[u].x), acc.x);
            acc.y = fmaf(a[u], bf2f(xv[u].y), acc.y);
            acc.z = fmaf(a[u], bf2f(xv[u].z), acc.z);
            acc.w = fmaf(a[u], bf2f(xv[u].w), acc.w);
        }
    }
    for (; j < e; j++) {
        int src = rfl(esrc[j]);
        float w = dinv[src] * ddst;
        ushort4 xv = *((const ushort4*)(H + (size_t)src * 256) + lane);
        acc.x = fmaf(w, bf2f(xv.x), acc.x);
        acc.y = fmaf(w, bf2f(xv.y), acc.y);
        acc.z = fmaf(w, bf2f(xv.z), acc.z);
        acc.w = fmaf(w, bf2f(xv.w), acc.w);
    }
    size_t o = (size_t)node * 256 + lane * 4;
    ushort4 hi;
    hi.x = f2bf(acc.x); hi.y = f2bf(acc.y);
    hi.z = f2bf(acc.z); hi.w = f2bf(acc.w);
    *(ushort4*)(Ah + o) = hi;
}

// ---------------- MFMA GEMM: C = relu(A @ W + b), 64x256 tile ----------
// One block = 64 output rows x all 256 cols (A read ONCE from HBM, grid.x only).
// A staged per 32-k-step through a 4/8 KB XOR-swizzled LDS tile; B fragments
// (weights, <=256 KB, L2-resident) loaded directly from global each k-step —
// no B staging, no redundant A fetch. Epilogue/fragment math identical to the
// verified previous kernel. ASPLIT: 3-term (Ah*Bh+Ah*Bl+Al*Bh) else 2-term.
template <int K, bool ASPLIT>
__global__ __launch_bounds__(256, 3) void mfma_gemm_bias_relu(const unsigned short* __restrict__ Ah,
                                                              const unsigned short* __restrict__ Al,
                                                              const unsigned short* __restrict__ Bh,
                                                              const unsigned short* __restrict__ Bl,
                                                              const float* __restrict__ bias,
                                                              unsigned short* __restrict__ Cout) {
    __shared__ __align__(16) unsigned char lds[(ASPLIT ? 2 : 1) * 4096];
    unsigned char* AhsB = lds;
    unsigned char* AlsB = lds + 4096;  // only touched when ASPLIT

    int tid = threadIdx.x;
    int wid = tid >> 6, lane = tid & 63;
    int lrow = lane & 15, quad = lane >> 4;
    int bm = blockIdx.x * 64;

    f32x4 acc[4][4];
#pragma unroll
    for (int mi = 0; mi < 4; mi++)
#pragma unroll
        for (int ni = 0; ni < 4; ni++) acc[mi][ni] = (f32x4){0.f, 0.f, 0.f, 0.f};

    int srow = tid >> 2, spart = tid & 3;  // staging: 64 rows x 4 parts of 16B
    unsigned sbo = ((unsigned)(srow * 64 + spart * 16)) ^ (((unsigned)(srow & 7)) << 4);

    for (int k0 = 0; k0 < K; k0 += 32) {
        // ---- stage A tile (64 x 32) ----
        {
            size_t ga = (size_t)(bm + srow) * K + k0 + spart * 8;
            ulonglong2 v = *(const ulonglong2*)(Ah + ga);
            *(ulonglong2*)(AhsB + sbo) = v;
            if (ASPLIT) {
                ulonglong2 v2 = *(const ulonglong2*)(Al + ga);
                *(ulonglong2*)(AlsB + sbo) = v2;
            }
        }
        __syncthreads();

        // ---- B fragments straight from global (L2-resident weights) ----
        bf16x8 bh[4], bl[4];
#pragma unroll
        for (int ni = 0; ni < 4; ni++) {
            int rowB = wid * 64 + ni * 16 + lrow;   // output column = B row
            size_t gb = (size_t)rowB * K + k0 + quad * 8;
            bh[ni] = *(const bf16x8*)(Bh + gb);
            bl[ni] = *(const bf16x8*)(Bl + gb);
        }

        // ---- A fragments from LDS ----
        bf16x8 ah[4], al[4];
#pragma unroll
        for (int mi = 0; mi < 4; mi++) {
            int r = mi * 16 + lrow;
            unsigned bo = ((unsigned)(r * 64 + quad * 16)) ^ (((unsigned)(r & 7)) << 4);
            ah[mi] = *(const bf16x8*)(AhsB + bo);
            if (ASPLIT) al[mi] = *(const bf16x8*)(AlsB + bo);
        }

#pragma unroll
        for (int ni = 0; ni < 4; ni++)
#pragma unroll
            for (int mi = 0; mi < 4; mi++) {
                acc[mi][ni] = __builtin_amdgcn_mfma_f32_16x16x32_bf16(ah[mi], bh[ni], acc[mi][ni], 0, 0, 0);
                acc[mi][ni] = __builtin_amdgcn_mfma_f32_16x16x32_bf16(ah[mi], bl[ni], acc[mi][ni], 0, 0, 0);
                if (ASPLIT)
                    acc[mi][ni] = __builtin_amdgcn_mfma_f32_16x16x32_bf16(al[mi], bh[ni], acc[mi][ni], 0, 0, 0);
            }
        __syncthreads();
    }

    // ---- epilogue: bias + relu + bf16 store ----
    float bv[4];
#pragma unroll
    for (int ni = 0; ni < 4; ni++) bv[ni] = bias[wid * 64 + ni * 16 + lrow];
#pragma unroll
    for (int mi = 0; mi < 4; mi++) {
        int row0 = bm + mi * 16 + quad * 4;
#pragma unroll
        for (int ni = 0; ni < 4; ni++) {
            int col = wid * 64 + ni * 16 + lrow;
#pragma unroll
            for (int rr = 0; rr < 4; rr++) {
                int row = row0 + rr;
                if (row < N_NODES) {
                    float v = fmaxf(acc[mi][ni][rr] + bv[ni], 0.f);
                    Cout[(size_t)row * 256 + col] = f2bf(v);
                }
            }
        }
    }
}

// ---------------- fused mean-pool (batch sorted, h in bf16) + MLP head ----------
__global__ __launch_bounds__(256) void pool_mlp_kernel(const unsigned short* __restrict__ h,
                                                       const int* __restrict__ batch,
                                                       const float* __restrict__ Wf1,
                                                       const float* __restrict__ bf1,
                                                       const float* __restrict__ Wf2,
                                                       const float* __restrict__ bf2,
                                                       float* __restrict__ out) {
    int g = blockIdx.x;
    int t = threadIdx.x;  // 0..255
    __shared__ int bounds[2];
    if (t < 2) {
        int target = g + t;
        int lo = 0, hi = N_NODES;
        while (lo < hi) {
            int mid = (lo + hi) >> 1;
            if (batch[mid] < target) lo = mid + 1;
            else hi = mid;
        }
        bounds[t] = lo;
    }
    __syncthreads();
    int lo = bounds[0], hi = bounds[1];

    float acc = 0.f;
    for (int n = lo; n < hi; n++) acc += bf2f(h[(size_t)n * HID + t]);
    float inv = (hi > lo) ? 1.0f / (float)(hi - lo) : 0.f;
    __shared__ float p[256];
    p[t] = acc * inv;
    __syncthreads();

    float hv = 0.f;
    if (t < 128) {
        float a = bf1[t];
#pragma unroll 8
        for (int k = 0; k < 256; k++) a = fmaf(p[k], Wf1[k * 128 + t], a);
        hv = fmaxf(a, 0.f) * Wf2[t];
    }
#pragma unroll
    for (int off = 32; off > 0; off >>= 1) hv += __shfl_down(hv, off, 64);
    __shared__ float partial[4];
    if ((t & 63) == 0) partial[t >> 6] = hv;
    __syncthreads();
    if (t == 0) out[g] = partial[0] + partial[1] + bf2[0];
}

extern "C" void kernel_launch(void* const* d_in, const int* in_sizes, int n_in,
                              void* d_out, int out_size, void* d_ws, size_t ws_size,
                              hipStream_t stream) {
    const float* x   = (const float*)d_in[0];
    const int*   ei  = (const int*)d_in[1];
    const int*   bat = (const int*)d_in[2];
    const float* W1  = (const float*)d_in[3];
    const float* b1  = (const float*)d_in[4];
    const float* W2  = (const float*)d_in[5];
    const float* b2  = (const float*)d_in[6];
    const float* Wf1 = (const float*)d_in[7];
    const float* bf1 = (const float*)d_in[8];
    const float* Wf2 = (const float*)d_in[9];
    const float* bf2 = (const float*)d_in[10];
    float* out = (float*)d_out;

    char* ws = (char*)d_ws;
    // layout (peak end 0x9B20000 = 162.5 MB):
    //   0x0000000 deg        0x0080000 dinv      0x0100000 rowptr   0x0180000 fill
    //   0x01F0000 bsum
    //   0x0200000 esrc (6.4 MB)
    //   0x0820000 W1th  0x0830000 W1tl  0x0840000 W2th  0x0860000 W2tl
    //   0x0880000 A1h (25.6 MB) / later A2 (51.2 MB, single)
    //   0x20F0000 A1l (25.6 MB)  [A2 overlaps A1h+A1l: both dead by then]
    //   0x6A40000 xbf (25.6 MB) -> H1bf (51.2 MB) -> H2bf (51.2 MB) time-multiplexed
    int*   deg    = (int*)(ws);
    float* dinv   = (float*)(ws + 0x0080000);
    int*   rowptr = (int*)(ws + 0x0100000);
    int*   fill   = (int*)(ws + 0x0180000);
    int*   bsum   = (int*)(ws + 0x01F0000);
    int*   esrc   = (int*)(ws + 0x0200000);
    unsigned short* W1th = (unsigned short*)(ws + 0x0820000);
    unsigned short* W1tl = (unsigned short*)(ws + 0x0830000);
    unsigned short* W2th = (unsigned short*)(ws + 0x0840000);
    unsigned short* W2tl = (unsigned short*)(ws + 0x0860000);
    unsigned short* A1h  = (unsigned short*)(ws + 0x0880000);
    unsigned short* A1l  = (unsigned short*)(ws + 0x20F0000);
    unsigned short* A2   = (unsigned short*)(ws + 0x0880000);  // reuses A1h+A1l space
    unsigned short* xbf  = (unsigned short*)(ws + 0x6A40000);
    unsigned short* H1bf = (unsigned short*)(ws + 0x6A40000);  // overwrites dead xbf
    unsigned short* H2bf = (unsigned short*)(ws + 0x6A40000);  // overwrites dead H1bf
    (void)ws_size;

    hipMemsetAsync(deg, 0, (size_t)N_NODES * sizeof(int), stream);
    hipMemsetAsync(fill, 0, (size_t)N_NODES * sizeof(int), stream);

    // independent prep
    x2bf_kernel<<<(N_NODES * IN_DIM / 4) / 256, 256, 0, stream>>>(x, xbf);
    wsplit_all_kernel<<<((IN_DIM + HID) * 256) / 256, 256, 0, stream>>>(W1, W2, W1th, W1tl, W2th, W2tl);

    // CSR build
    count_deg_kernel<<<(N_EDGES + 255) / 256, 256, 0, stream>>>(ei, deg);
    blocksum_kernel<<<SCAN_BLOCKS, 1024, 0, stream>>>(deg, bsum, dinv);
    bscan_kernel<<<1, 128, 0, stream>>>(bsum);
    scanout_kernel<<<SCAN_BLOCKS, 1024, 0, stream>>>(deg, bsum, rowptr);
    fill_kernel<<<(N_EDGES + 255) / 256, 256, 0, stream>>>(ei, rowptr, fill, esrc);

    // layer 1: A1 = split(A~ x_bf16); H1bf = bf16(relu(A1 @ W1 + b1))  [3-term]
    agg128_kernel<<<N_NODES / 4, 256, 0, stream>>>(xbf, esrc, rowptr, dinv, A1h, A1l);
    mfma_gemm_bias_relu<IN_DIM, true><<<M_PAD / 64, 256, 0, stream>>>(A1h, A1l, W1th, W1tl, b1, H1bf);

    // layer 2: A2 = bf16(A~ H1bf); H2bf = bf16(relu(A2 @ W2 + b2))  [2-term]
    agg256_kernel<<<N_NODES / 4, 256, 0, stream>>>(H1bf, esrc, rowptr, dinv, A2);
    mfma_gemm_bias_relu<HID, false><<<M_PAD / 64, 256, 0, stream>>>(A2, nullptr, W2th, W2tl, b2, H2bf);

    // pooling + MLP head (bf16 h)
    pool_mlp_kernel<<<NUM_GRAPHS, 256, 0, stream>>>(H2bf, bat, Wf1, bf1, Wf2, bf2, out);
}

// Round 4
// 545.465 us; speedup vs baseline: 1.1675x; 1.1586x over previous
//
#include <hip/hip_runtime.h>
#include <hip/hip_bf16.h>

#define N_NODES 100000
#define N_EDGES 1600000
#define IN_DIM 128
#define HID 256
#define NUM_GRAPHS 2048
#define M_PAD 100096  // 782 * 128
#define SCAN_BLOCKS 98  // ceil(100000/1024)

typedef __bf16 bf16x8 __attribute__((ext_vector_type(8)));
typedef float f32x4 __attribute__((ext_vector_type(4)));

__device__ inline unsigned short f2bf(float x) {
    union { __hip_bfloat16 h; unsigned short u; } v;
    v.h = __float2bfloat16(x);
    return v.u;
}
__device__ inline float bf2f(unsigned short u) {
    return __uint_as_float(((unsigned int)u) << 16);
}
__device__ inline int rfl(int x) { return __builtin_amdgcn_readfirstlane(x); }

// ---------------- degree histogram over dst + per-edge ordinal ----------------
// atomicAdd's return value IS the edge's within-dst ordinal: saves the second
// 1.6M-random-atomic pass that fill_kernel used to do.
__global__ void count_deg_kernel(const int* __restrict__ ei, int* __restrict__ deg,
                                 int* __restrict__ eord) {
    int e = blockIdx.x * blockDim.x + threadIdx.x;
    if (e < N_EDGES) {
        eord[e] = atomicAdd(&deg[ei[N_EDGES + e]], 1);
    }
}

// ---------------- block sums (+ fused dinv) ----------------
__global__ __launch_bounds__(1024) void blocksum_kernel(const int* __restrict__ deg,
                                                        int* __restrict__ bsum,
                                                        float* __restrict__ dinv) {
    int i = blockIdx.x * 1024 + threadIdx.x;
    int v = (i < N_NODES) ? deg[i] : 0;
    if (i < N_NODES) dinv[i] = rsqrtf((float)(v + 1));  // self-loop adds 1
    __shared__ int s[1024];
    int t = threadIdx.x;
    s[t] = v;
    __syncthreads();
#pragma unroll
    for (int off = 512; off > 0; off >>= 1) {
        if (t < off) s[t] += s[t + off];
        __syncthreads();
    }
    if (t == 0) bsum[blockIdx.x] = s[0];
}

__global__ __launch_bounds__(128) void bscan_kernel(int* __restrict__ bsum) {
    __shared__ int s[128];
    int t = threadIdx.x;
    int v = (t < SCAN_BLOCKS) ? bsum[t] : 0;
    s[t] = v;
    __syncthreads();
#pragma unroll
    for (int off = 1; off < 128; off <<= 1) {
        int x = (t >= off) ? s[t - off] : 0;
        __syncthreads();
        s[t] += x;
        __syncthreads();
    }
    if (t < SCAN_BLOCKS) bsum[t] = (t > 0) ? s[t - 1] : 0;  // exclusive
}

__global__ __launch_bounds__(1024) void scanout_kernel(const int* __restrict__ deg,
                                                       const int* __restrict__ bsum,
                                                       int* __restrict__ rowptr) {
    int i = blockIdx.x * 1024 + threadIdx.x;
    int t = threadIdx.x;
    int v = (i < N_NODES) ? deg[i] : 0;
    __shared__ int s[1024];
    s[t] = v;
    __syncthreads();
#pragma unroll
    for (int off = 1; off < 1024; off <<= 1) {
        int x = (t >= off) ? s[t - off] : 0;
        __syncthreads();
        s[t] += x;
        __syncthreads();
    }
    int base = bsum[blockIdx.x];
    int excl = (t > 0) ? s[t - 1] : 0;
    if (i < N_NODES) rowptr[i] = base + excl;
    if (i == N_NODES - 1) rowptr[N_NODES] = base + s[t];
}

// ---------------- bucket fill: CSR src list sorted by dst (atomic-free) ----------
__global__ void fill_kernel(const int* __restrict__ ei, const int* __restrict__ rowptr,
                            const int* __restrict__ eord, int* __restrict__ esrc) {
    int e = blockIdx.x * blockDim.x + threadIdx.x;
    if (e < N_EDGES) {
        int dst = ei[N_EDGES + e];
        esrc[rowptr[dst] + eord[e]] = ei[e];
    }
}

// ---------------- x -> bf16 ----------------
__global__ void x2bf_kernel(const float* __restrict__ x, unsigned short* __restrict__ xb) {
    size_t i = ((size_t)blockIdx.x * 256 + threadIdx.x) * 4;
    float4 v = *(const float4*)(x + i);
    ushort4 o;
    o.x = f2bf(v.x); o.y = f2bf(v.y); o.z = f2bf(v.z); o.w = f2bf(v.w);
    *(ushort4*)(xb + i) = o;
}

// ---------------- both weight transposes + bf16 splits in one launch ----------
__global__ void wsplit_all_kernel(const float* __restrict__ W1, const float* __restrict__ W2,
                                  unsigned short* __restrict__ W1th, unsigned short* __restrict__ W1tl,
                                  unsigned short* __restrict__ W2th, unsigned short* __restrict__ W2tl) {
    int idx = blockIdx.x * 256 + threadIdx.x;
    if (idx < IN_DIM * 256) {
        int k = idx >> 8, n = idx & 255;
        float w = W1[idx];
        unsigned short h = f2bf(w);
        unsigned short l = f2bf(w - bf2f(h));
        W1th[n * IN_DIM + k] = h;
        W1tl[n * IN_DIM + k] = l;
    } else {
        int i2 = idx - IN_DIM * 256;
        int k = i2 >> 8, n = i2 & 255;
        float w = W2[i2];
        unsigned short h = f2bf(w);
        unsigned short l = f2bf(w - bf2f(h));
        W2th[n * HID + k] = h;
        W2tl[n * HID + k] = l;
    }
}

// ---------------- gather agg 128-dim from bf16, writes bf16 hi/lo split ----------
// wave-uniform node/s/e/src via readfirstlane -> scalar addressing for gathers
__global__ __launch_bounds__(256) void agg128_kernel(const unsigned short* __restrict__ X,
                                                     const int* __restrict__ esrc,
                                                     const int* __restrict__ rowptr,
                                                     const float* __restrict__ dinv,
                                                     unsigned short* __restrict__ Ah,
                                                     unsigned short* __restrict__ Al) {
    int node = rfl(blockIdx.x * 4 + (threadIdx.x >> 6));
    int lane = threadIdx.x & 63;
    float ddst = dinv[node];
    int s = rfl(rowptr[node]);
    int e = rfl(rowptr[node + 1]);

    float w0 = ddst * ddst;
    ushort2 h0 = *((const ushort2*)(X + (size_t)node * 128) + lane);
    float2 acc = make_float2(w0 * bf2f(h0.x), w0 * bf2f(h0.y));

    int j = s;
    for (; j + 8 <= e; j += 8) {
        int si[8];
#pragma unroll
        for (int u = 0; u < 8; u++) si[u] = rfl(esrc[j + u]);
        ushort2 xv[8];
#pragma unroll
        for (int u = 0; u < 8; u++)
            xv[u] = *((const ushort2*)(X + (size_t)si[u] * 128) + lane);
        float a[8];
#pragma unroll
        for (int u = 0; u < 8; u++) a[u] = dinv[si[u]] * ddst;
#pragma unroll
        for (int u = 0; u < 8; u++) {
            acc.x = fmaf(a[u], bf2f(xv[u].x), acc.x);
            acc.y = fmaf(a[u], bf2f(xv[u].y), acc.y);
        }
    }
    for (; j + 4 <= e; j += 4) {
        int si[4];
#pragma unroll
        for (int u = 0; u < 4; u++) si[u] = rfl(esrc[j + u]);
        ushort2 xv[4];
#pragma unroll
        for (int u = 0; u < 4; u++)
            xv[u] = *((const ushort2*)(X + (size_t)si[u] * 128) + lane);
        float a[4];
#pragma unroll
        for (int u = 0; u < 4; u++) a[u] = dinv[si[u]] * ddst;
#pragma unroll
        for (int u = 0; u < 4; u++) {
            acc.x = fmaf(a[u], bf2f(xv[u].x), acc.x);
            acc.y = fmaf(a[u], bf2f(xv[u].y), acc.y);
        }
    }
    for (; j < e; j++) {
        int src = rfl(esrc[j]);
        float w = dinv[src] * ddst;
        ushort2 xv = *((const ushort2*)(X + (size_t)src * 128) + lane);
        acc.x = fmaf(w, bf2f(xv.x), acc.x);
        acc.y = fmaf(w, bf2f(xv.y), acc.y);
    }
    size_t o = (size_t)node * 128 + lane * 2;
    ushort2 hi, lo;
    hi.x = f2bf(acc.x); lo.x = f2bf(acc.x - bf2f(hi.x));
    hi.y = f2bf(acc.y); lo.y = f2bf(acc.y - bf2f(hi.y));
    *(ushort2*)(Ah + o) = hi;
    *(ushort2*)(Al + o) = lo;
}

// ---------------- gather agg 256-dim from bf16, writes bf16 (hi only) ----------
__global__ __launch_bounds__(256) void agg256_kernel(const unsigned short* __restrict__ H,
                                                     const int* __restrict__ esrc,
                                                     const int* __restrict__ rowptr,
                                                     const float* __restrict__ dinv,
                                                     unsigned short* __restrict__ Ah) {
    int node = rfl(blockIdx.x * 4 + (threadIdx.x >> 6));
    int lane = threadIdx.x & 63;
    float ddst = dinv[node];
    int s = rfl(rowptr[node]);
    int e = rfl(rowptr[node + 1]);

    float w0 = ddst * ddst;
    ushort4 h0 = *((const ushort4*)(H + (size_t)node * 256) + lane);
    float4 acc = make_float4(w0 * bf2f(h0.x), w0 * bf2f(h0.y),
                             w0 * bf2f(h0.z), w0 * bf2f(h0.w));

    int j = s;
    for (; j + 8 <= e; j += 8) {
        int si[8];
#pragma unroll
        for (int u = 0; u < 8; u++) si[u] = rfl(esrc[j + u]);
        ushort4 xv[8];
#pragma unroll
        for (int u = 0; u < 8; u++)
            xv[u] = *((const ushort4*)(H + (size_t)si[u] * 256) + lane);
        float a[8];
#pragma unroll
        for (int u = 0; u < 8; u++) a[u] = dinv[si[u]] * ddst;
#pragma unroll
        for (int u = 0; u < 8; u++) {
            acc.x = fmaf(a[u], bf2f(xv[u].x), acc.x);
            acc.y = fmaf(a[u], bf2f(xv[u].y), acc.y);
            acc.z = fmaf(a[u], bf2f(xv[u].z), acc.z);
            acc.w = fmaf(a[u], bf2f(xv[u].w), acc.w);
        }
    }
    for (; j + 4 <= e; j += 4) {
        int si[4];
#pragma unroll
        for (int u = 0; u < 4; u++) si[u] = rfl(esrc[j + u]);
        ushort4 xv[4];
#pragma unroll
        for (int u = 0; u < 4; u++)
            xv[u] = *((const ushort4*)(H + (size_t)si[u] * 256) + lane);
        float a[4];
#pragma unroll
        for (int u = 0; u < 4; u++) a[u] = dinv[si[u]] * ddst;
#pragma unroll
        for (int u = 0; u < 4; u++) {
            acc.x = fmaf(a[u], bf2f(xv[u].x), acc.x);
            acc.y = fmaf(a[u], bf2f(xv[u].y), acc.y);
            acc.z = fmaf(a[u], bf2f(xv[u].z), acc.z);
            acc.w = fmaf(a[u], bf2f(xv[u].w), acc.w);
        }
    }
    for (; j < e; j++) {
        int src = rfl(esrc[j]);
        float w = dinv[src] * ddst;
        ushort4 xv = *((const ushort4*)(H + (size_t)src * 256) + lane);
        acc.x = fmaf(w, bf2f(xv.x), acc.x);
        acc.y = fmaf(w, bf2f(xv.y), acc.y);
        acc.z = fmaf(w, bf2f(xv.z), acc.z);
        acc.w = fmaf(w, bf2f(xv.w), acc.w);
    }
    size_t o = (size_t)node * 256 + lane * 4;
    ushort4 hi;
    hi.x = f2bf(acc.x); hi.y = f2bf(acc.y);
    hi.z = f2bf(acc.z); hi.w = f2bf(acc.w);
    *(ushort4*)(Ah + o) = hi;
}

// ---------------- MFMA GEMM: C = relu(A @ W + b) ----------
// ASPLIT: A has hi+lo (3-term product) else hi only (2-term). Output bf16.
// (round-0 proven version: 128x128 tile, grid.y=2)
template <int K, bool ASPLIT>
__launch_bounds__(256, 2)
__global__ void mfma_gemm_bias_relu(const unsigned short* __restrict__ Ah,
                                    const unsigned short* __restrict__ Al,
                                    const unsigned short* __restrict__ Bh,
                                    const unsigned short* __restrict__ Bl,
                                    const float* __restrict__ bias,
                                    unsigned short* __restrict__ Cout) {
    constexpr int NT = ASPLIT ? 4 : 3;
    __shared__ __align__(16) unsigned short lds[NT * 128 * 32];
    unsigned short* Ahs = lds;
    unsigned short* Als = lds + 4096;                    // only valid if ASPLIT
    unsigned short* Bhs = lds + (ASPLIT ? 8192 : 4096);
    unsigned short* Bls = lds + (ASPLIT ? 12288 : 8192);

    int tid = threadIdx.x;
    int bm = blockIdx.x * 128;
    int bn = blockIdx.y * 128;
    int wid = tid >> 6, lane = tid & 63;
    int wm = wid & 1, wn = wid >> 1;
    int lrow = lane & 15, quad = lane >> 4;

    f32x4 acc[4][4];
#pragma unroll
    for (int mi = 0; mi < 4; mi++)
#pragma unroll
        for (int ni = 0; ni < 4; ni++) acc[mi][ni] = (f32x4){0.f, 0.f, 0.f, 0.f};

    for (int k0 = 0; k0 < K; k0 += 32) {
#pragma unroll
        for (int i = 0; i < NT * 2; i++) {
            int c = tid + 256 * i;
            int tile = c >> 9;
            int w = c & 511;
            int row = w >> 2;
            int part = w & 3;
            const unsigned short* g;
            if (ASPLIT) {
                if (tile == 0)      g = Ah + (size_t)(bm + row) * K + k0 + part * 8;
                else if (tile == 1) g = Al + (size_t)(bm + row) * K + k0 + part * 8;
                else if (tile == 2) g = Bh + (size_t)(bn + row) * K + k0 + part * 8;
                else                g = Bl + (size_t)(bn + row) * K + k0 + part * 8;
            } else {
                if (tile == 0)      g = Ah + (size_t)(bm + row) * K + k0 + part * 8;
                else if (tile == 1) g = Bh + (size_t)(bn + row) * K + k0 + part * 8;
                else                g = Bl + (size_t)(bn + row) * K + k0 + part * 8;
            }
            ulonglong2 v = *(const ulonglong2*)g;
            *(ulonglong2*)&lds[(tile << 12) + row * 32 + part * 8] = v;
        }
        __syncthreads();

        bf16x8 ah[4], al[4], bh[4], bl[4];
#pragma unroll
        for (int mi = 0; mi < 4; mi++) {
            int r = wm * 64 + mi * 16 + lrow;
            ah[mi] = *(const bf16x8*)&Ahs[r * 32 + quad * 8];
            if (ASPLIT) al[mi] = *(const bf16x8*)&Als[r * 32 + quad * 8];
        }
#pragma unroll
        for (int ni = 0; ni < 4; ni++) {
            int r = wn * 64 + ni * 16 + lrow;
            bh[ni] = *(const bf16x8*)&Bhs[r * 32 + quad * 8];
            bl[ni] = *(const bf16x8*)&Bls[r * 32 + quad * 8];
        }
#pragma unroll
        for (int mi = 0; mi < 4; mi++)
#pragma unroll
            for (int ni = 0; ni < 4; ni++) {
                acc[mi][ni] = __builtin_amdgcn_mfma_f32_16x16x32_bf16(ah[mi], bh[ni], acc[mi][ni], 0, 0, 0);
                acc[mi][ni] = __builtin_amdgcn_mfma_f32_16x16x32_bf16(ah[mi], bl[ni], acc[mi][ni], 0, 0, 0);
                if (ASPLIT)
                    acc[mi][ni] = __builtin_amdgcn_mfma_f32_16x16x32_bf16(al[mi], bh[ni], acc[mi][ni], 0, 0, 0);
            }
        __syncthreads();
    }

    float bv[4];
#pragma unroll
    for (int ni = 0; ni < 4; ni++) bv[ni] = bias[bn + wn * 64 + ni * 16 + lrow];
#pragma unroll
    for (int mi = 0; mi < 4; mi++) {
        int row0 = bm + wm * 64 + mi * 16 + quad * 4;
#pragma unroll
        for (int ni = 0; ni < 4; ni++) {
            int col = bn + wn * 64 + ni * 16 + lrow;
#pragma unroll
            for (int r = 0; r < 4; r++) {
                int row = row0 + r;
                if (row < N_NODES) {
                    float v = fmaxf(acc[mi][ni][r] + bv[ni], 0.f);
                    Cout[(size_t)row * 256 + col] = f2bf(v);
                }
            }
        }
    }
}

// ---------------- fused mean-pool (batch sorted, h in bf16) + MLP head ----------
__global__ __launch_bounds__(256) void pool_mlp_kernel(const unsigned short* __restrict__ h,
                                                       const int* __restrict__ batch,
                                                       const float* __restrict__ Wf1,
                                                       const float* __restrict__ bf1,
                                                       const float* __restrict__ Wf2,
                                                       const float* __restrict__ bf2,
                                                       float* __restrict__ out) {
    int g = blockIdx.x;
    int t = threadIdx.x;  // 0..255
    __shared__ int bounds[2];
    if (t < 2) {
        int target = g + t;
        int lo = 0, hi = N_NODES;
        while (lo < hi) {
            int mid = (lo + hi) >> 1;
            if (batch[mid] < target) lo = mid + 1;
            else hi = mid;
        }
        bounds[t] = lo;
    }
    __syncthreads();
    int lo = bounds[0], hi = bounds[1];

    float acc = 0.f;
    for (int n = lo; n < hi; n++) acc += bf2f(h[(size_t)n * HID + t]);
    float inv = (hi > lo) ? 1.0f / (float)(hi - lo) : 0.f;
    __shared__ float p[256];
    p[t] = acc * inv;
    __syncthreads();

    float hv = 0.f;
    if (t < 128) {
        float a = bf1[t];
#pragma unroll 8
        for (int k = 0; k < 256; k++) a = fmaf(p[k], Wf1[k * 128 + t], a);
        hv = fmaxf(a, 0.f) * Wf2[t];
    }
#pragma unroll
    for (int off = 32; off > 0; off >>= 1) hv += __shfl_down(hv, off, 64);
    __shared__ float partial[4];
    if ((t & 63) == 0) partial[t >> 6] = hv;
    __syncthreads();
    if (t == 0) out[g] = partial[0] + partial[1] + bf2[0];
}

extern "C" void kernel_launch(void* const* d_in, const int* in_sizes, int n_in,
                              void* d_out, int out_size, void* d_ws, size_t ws_size,
                              hipStream_t stream) {
    const float* x   = (const float*)d_in[0];
    const int*   ei  = (const int*)d_in[1];
    const int*   bat = (const int*)d_in[2];
    const float* W1  = (const float*)d_in[3];
    const float* b1  = (const float*)d_in[4];
    const float* W2  = (const float*)d_in[5];
    const float* b2  = (const float*)d_in[6];
    const float* Wf1 = (const float*)d_in[7];
    const float* bf1 = (const float*)d_in[8];
    const float* Wf2 = (const float*)d_in[9];
    const float* bf2 = (const float*)d_in[10];
    float* out = (float*)d_out;

    char* ws = (char*)d_ws;
    // layout (peak end 0x9B20000 = 162.5 MB):
    //   0x0000000 deg        0x0080000 dinv      0x0100000 rowptr
    //   0x01F0000 bsum
    //   0x0200000 esrc (6.4 MB)
    //   0x0820000 W1th  0x0830000 W1tl  0x0840000 W2th  0x0860000 W2tl
    //   0x0880000 A1h (25.6 MB) / later A2 (51.2 MB, single)
    //   0x20F0000 eord (6.4 MB, dead after fill) -> A1l (25.6 MB)  [A2 overlaps]
    //   0x6A40000 xbf (25.6 MB) -> H1bf (51.2 MB) -> H2bf (51.2 MB) time-multiplexed
    int*   deg    = (int*)(ws);
    float* dinv   = (float*)(ws + 0x0080000);
    int*   rowptr = (int*)(ws + 0x0100000);
    int*   bsum   = (int*)(ws + 0x01F0000);
    int*   esrc   = (int*)(ws + 0x0200000);
    unsigned short* W1th = (unsigned short*)(ws + 0x0820000);
    unsigned short* W1tl = (unsigned short*)(ws + 0x0830000);
    unsigned short* W2th = (unsigned short*)(ws + 0x0840000);
    unsigned short* W2tl = (unsigned short*)(ws + 0x0860000);
    unsigned short* A1h  = (unsigned short*)(ws + 0x0880000);
    int*   eord   = (int*)(ws + 0x20F0000);                    // dead before A1l written
    unsigned short* A1l  = (unsigned short*)(ws + 0x20F0000);
    unsigned short* A2   = (unsigned short*)(ws + 0x0880000);  // reuses A1h+A1l space
    unsigned short* xbf  = (unsigned short*)(ws + 0x6A40000);
    unsigned short* H1bf = (unsigned short*)(ws + 0x6A40000);  // overwrites dead xbf
    unsigned short* H2bf = (unsigned short*)(ws + 0x6A40000);  // overwrites dead H1bf
    (void)ws_size;

    hipMemsetAsync(deg, 0, (size_t)N_NODES * sizeof(int), stream);

    // independent prep
    x2bf_kernel<<<(N_NODES * IN_DIM / 4) / 256, 256, 0, stream>>>(x, xbf);
    wsplit_all_kernel<<<((IN_DIM + HID) * 256) / 256, 256, 0, stream>>>(W1, W2, W1th, W1tl, W2th, W2tl);

    // CSR build (ordinal trick: count_deg's atomic return value is the slot index,
    // so fill_kernel is atomic-free)
    count_deg_kernel<<<(N_EDGES + 255) / 256, 256, 0, stream>>>(ei, deg, eord);
    blocksum_kernel<<<SCAN_BLOCKS, 1024, 0, stream>>>(deg, bsum, dinv);
    bscan_kernel<<<1, 128, 0, stream>>>(bsum);
    scanout_kernel<<<SCAN_BLOCKS, 1024, 0, stream>>>(deg, bsum, rowptr);
    fill_kernel<<<(N_EDGES + 255) / 256, 256, 0, stream>>>(ei, rowptr, eord, esrc);

    // layer 1: A1 = split(A~ x_bf16); H1bf = bf16(relu(A1 @ W1 + b1))  [3-term]
    agg128_kernel<<<N_NODES / 4, 256, 0, stream>>>(xbf, esrc, rowptr, dinv, A1h, A1l);
    {
        dim3 grid(M_PAD / 128, 2);
        mfma_gemm_bias_relu<IN_DIM, true><<<grid, 256, 0, stream>>>(A1h, A1l, W1th, W1tl, b1, H1bf);
    }

    // layer 2: A2 = bf16(A~ H1bf); H2bf = bf16(relu(A2 @ W2 + b2))  [2-term]
    agg256_kernel<<<N_NODES / 4, 256, 0, stream>>>(H1bf, esrc, rowptr, dinv, A2);
    {
        dim3 grid(M_PAD / 128, 2);
        mfma_gemm_bias_relu<HID, false><<<grid, 256, 0, stream>>>(A2, nullptr, W2th, W2tl, b2, H2bf);
    }

    // pooling + MLP head (bf16 h)
    pool_mlp_kernel<<<NUM_GRAPHS, 256, 0, stream>>>(H2bf, bat, Wf1, bf1, Wf2, bf2, out);
}